// Round 1
// baseline (561.168 us; speedup 1.0000x reference)
//
#include <hip/hip_runtime.h>

// B=4, S=4096, H=512, K=2, D=8, experts=64
// T = 16384 tokens; out: [8, 32768, 512] fp32 = 512 MiB
#define NDEV    8
#define TOK     16384
#define TKROWS  (TOK * 2)                 // 32768 (token,k) rows
#define COLS    128                       // float4 per row (H=512)
#define DSTRIDE ((size_t)TKROWS * COLS)   // float4 elems per device section

typedef float f4 __attribute__((ext_vector_type(4)));

// Single-pass fused dispatch: each thread owns one (tk, col) 16-B chunk and
// writes it into ALL 8 device sections — the routed device gets the token
// data, the other 7 get zeros. Every output cache line is written exactly
// once (no memset prepass, no double-write of live slots).
//
// Traffic: 512 MiB NT-stores + 32 MiB x-reads (each token row read once from
// HBM: block b covers tk={2b,2b+1}, both share t=b, second read hits L1).
// Roofline at 6.3 TB/s streaming: ~90 us.
__global__ __launch_bounds__(256)
void a2a_dispatch_kernel(const f4*  __restrict__ x,     // [TOK, COLS]
                         const int* __restrict__ eidx,  // [TKROWS]
                         const int* __restrict__ emap,  // [64]
                         f4*        __restrict__ out)   // [NDEV, TKROWS, COLS]
{
    const int idx = blockIdx.x * 256 + threadIdx.x;   // [0, TKROWS*COLS)
    const int col = idx & (COLS - 1);
    const int tk  = idx >> 7;
    const int t   = tk >> 1;                          // token id (K=2)

    // Wave-uniform per row (64 lanes span one half-row of one tk).
    const int dev = emap[eidx[tk]];                   // in [0, NDEV)

    const f4 v = x[(size_t)t * COLS + col];
    const f4 z = {0.f, 0.f, 0.f, 0.f};

    // 8 coalesced 1 KiB wave-stores, one per device section; exactly one
    // carries data. d==dev is wave-uniform -> cndmask, no divergence.
#pragma unroll
    for (int d = 0; d < NDEV; ++d) {
        __builtin_nontemporal_store(d == dev ? v : z,
                                    &out[(size_t)d * DSTRIDE + idx]);
    }
}

extern "C" void kernel_launch(void* const* d_in, const int* in_sizes, int n_in,
                              void* d_out, int out_size, void* d_ws, size_t ws_size,
                              hipStream_t stream) {
    const f4*  x    = (const f4*)d_in[0];
    const int* eidx = (const int*)d_in[1];
    const int* emap = (const int*)d_in[2];
    f4*        out  = (f4*)d_out;

    // NOTE: no memset prepass. The old hipMemsetAsync(out_size*sizeof(float))
    // was measured (WRITE_SIZE=2.147GB/dispatch) to zero 4x the 512 MiB
    // output — out_size is a byte count. The fused kernel writes every
    // output line exactly once, so no background fill is needed at all.

    const int block = 256;
    const int grid  = (TKROWS * COLS) / block;        // 16384 blocks
    a2a_dispatch_kernel<<<grid, block, 0, stream>>>(x, eidx, emap, out);
}

// Round 2
// 548.733 us; speedup vs baseline: 1.0227x; 1.0227x over previous
//
#include <hip/hip_runtime.h>

// B=4, S=4096, H=512, K=2, D=8, experts=64
// T = 16384 tokens; out: [8, 32768, 512] fp32 = 512 MiB
#define NDEV    8
#define TOK     16384
#define TKROWS  (TOK * 2)                 // 32768 (token,k) rows
#define COLS    128                       // float4 per row (H=512)
#define DSTRIDE ((size_t)TKROWS * COLS)   // float4 elems per device section

typedef float f4 __attribute__((ext_vector_type(4)));

// Single-pass fused dispatch: each thread owns one (tk, col) 16-B chunk and
// writes it into ALL 8 device sections — the routed device gets the token
// data, the other 7 get zeros. Every output cache line is written exactly
// once (no memset prepass, no double-write of live slots).
//
// Round-2 change vs round 1: PLAIN stores instead of nontemporal. The
// rocclr fill kernel sustains 6.2 TB/s on this exact buffer with plain
// stores; NT stores (16 B/lane write-through, no L2 line aggregation)
// measured ~2.5 TB/s. Let L2 combine full 128 B dirty lines.
__global__ __launch_bounds__(256)
void a2a_dispatch_kernel(const f4*  __restrict__ x,     // [TOK, COLS]
                         const int* __restrict__ eidx,  // [TKROWS]
                         const int* __restrict__ emap,  // [64]
                         f4*        __restrict__ out)   // [NDEV, TKROWS, COLS]
{
    const int idx = blockIdx.x * 256 + threadIdx.x;   // [0, TKROWS*COLS)
    const int col = idx & (COLS - 1);
    const int tk  = idx >> 7;
    const int t   = tk >> 1;                          // token id (K=2)

    // Wave-uniform per row (64 lanes span one half-row of one tk).
    const int dev = emap[eidx[tk]];                   // in [0, NDEV)

    const f4 v = x[(size_t)t * COLS + col];
    const f4 z = {0.f, 0.f, 0.f, 0.f};

    // 8 coalesced 1 KiB wave-stores, one per device section; exactly one
    // carries data. d==dev is wave-uniform -> cndmask, no divergence.
#pragma unroll
    for (int d = 0; d < NDEV; ++d) {
        out[(size_t)d * DSTRIDE + idx] = (d == dev) ? v : z;
    }
}

extern "C" void kernel_launch(void* const* d_in, const int* in_sizes, int n_in,
                              void* d_out, int out_size, void* d_ws, size_t ws_size,
                              hipStream_t stream) {
    const f4*  x    = (const f4*)d_in[0];
    const int* eidx = (const int*)d_in[1];
    const int* emap = (const int*)d_in[2];
    f4*        out  = (f4*)d_out;

    // No memset prepass: the fused kernel writes every output line exactly
    // once. (The recurring 2.147 GB fillBufferAligned dispatches in the
    // profile are the harness's per-iteration output re-poison, not ours.)
    const int block = 256;
    const int grid  = (TKROWS * COLS) / block;        // 16384 blocks
    a2a_dispatch_kernel<<<grid, block, 0, stream>>>(x, eidx, emap, out);
}